// Round 11
// baseline (21.362 us; speedup 1.0000x reference)
//
#include <hip/hip_runtime.h>

#define EPSF 1e-7f

__device__ __forceinline__ float rcp_fast(float x) { return __builtin_amdgcn_rcpf(x); }

// LDS float4-chunk swizzle: spreads strided row reads across bank groups.
__device__ __forceinline__ int swz(int r, int c) { return r * 16 + (c ^ ((r >> 2) & 7)); }

__device__ __forceinline__ float dot4(float4 v) {
    return v.x * v.x + v.y * v.y + v.z * v.z + v.w * v.w;
}

// K1: 32(i) x 64(j) tile, 512 blocks x 512 threads = 4 waves/SIMD.
// xi held in REGISTERS (wave-uniform 4-row group x 16-dim quarter = 64 VGPR,
// broadcast global loads); LDS only stages the j-tile. Thread (q,h2) computes
// 4x4 quarter-dots; shfl_xor(1),(2) combine; lane h2 maps col jb+h2 for its 4 rows.
__global__ __launch_bounds__(512, 4) void pair_kernel(
    const float* __restrict__ x, const int* __restrict__ adj,
    float* __restrict__ T, float* __restrict__ alphaPart) {
    const int N = 1024;
    const int j0 = blockIdx.x * 64;
    const int i0 = blockIdx.y * 32;
    const int t = threadIdx.x;       // 0..511
    const int h2 = t & 3;            // dim quarter / col select
    const int q = t >> 2;            // 0..127
    const int qx = q & 15;           // j quad
    const int qy = q >> 4;           // 0..7 (wave-uniform: 4-row group)

    __shared__ float4 tj4[64 * 16];  // 16 KB
    __shared__ float y2_l[64];

    const float4* x4 = reinterpret_cast<const float4*>(x);
    // stage j-tile (coalesced) + y2 norms via 16-lane butterfly
#pragma unroll
    for (int k = 0; k < 2; ++k) {
        const int f = k * 512 + t;
        const int r = f >> 4, c = f & 15;
        float4 v = x4[(size_t)j0 * 16 + f];
        tj4[swz(r, c)] = v;
        float s = dot4(v);
#pragma unroll
        for (int off = 1; off <= 8; off <<= 1) s += __shfl_xor(s, off, 64);
        if ((t & 15) == 0) y2_l[r] = s;
    }

    // xi -> registers: 4 rows x dim-quarter h2 (16 float4). Broadcast loads:
    // per instruction only 4 distinct 16B addresses (one 64B line).
    const int ib = i0 + qy * 4;
    float4 xi[4][4];
    float x2a4[4];
#pragma unroll
    for (int a = 0; a < 4; ++a) {
        float s = 0.f;
#pragma unroll
        for (int c = 0; c < 4; ++c) {
            xi[a][c] = x4[(size_t)(ib + a) * 16 + h2 * 4 + c];
            s += dot4(xi[a][c]);
        }
        x2a4[a] = s;  // quarter norm
    }
    // combine dim-quarters for row norms (lane bits 0,1)
#pragma unroll
    for (int a = 0; a < 4; ++a) {
        x2a4[a] += __shfl_xor(x2a4[a], 1, 64);
        x2a4[a] += __shfl_xor(x2a4[a], 2, 64);
    }
    __syncthreads();

    float acc[4][4];
#pragma unroll
    for (int a = 0; a < 4; ++a)
#pragma unroll
        for (int b = 0; b < 4; ++b) acc[a][b] = 0.f;

#pragma unroll
    for (int cc = 0; cc < 4; ++cc) {
        const int c = h2 * 4 + cc;
        float4 xjv[4];
#pragma unroll
        for (int b = 0; b < 4; ++b) xjv[b] = tj4[swz(qx * 4 + b, c)];
#pragma unroll
        for (int a = 0; a < 4; ++a)
#pragma unroll
            for (int b = 0; b < 4; ++b) {
                acc[a][b] = fmaf(xi[a][cc].x, xjv[b].x, acc[a][b]);
                acc[a][b] = fmaf(xi[a][cc].y, xjv[b].y, acc[a][b]);
                acc[a][b] = fmaf(xi[a][cc].z, xjv[b].z, acc[a][b]);
                acc[a][b] = fmaf(xi[a][cc].w, xjv[b].w, acc[a][b]);
            }
    }
    // combine dim-quarters (lane bits 0,1): all quad lanes end with full dots
#pragma unroll
    for (int a = 0; a < 4; ++a)
#pragma unroll
        for (int b = 0; b < 4; ++b) {
            acc[a][b] += __shfl_xor(acc[a][b], 1, 64);
            acc[a][b] += __shfl_xor(acc[a][b], 2, 64);
        }

    const int jb = j0 + qx * 4;
    const int jcol = jb + h2;        // this lane's column
    const float y2c = y2_l[qx * 4 + h2];

    float svsum[4];
#pragma unroll
    for (int a = 0; a < 4; ++a) {
        const int m = adj[(size_t)(ib + a) * N + jcol];
        const float x2a = x2a4[a];
        const float onemx2 = 1.f - x2a;
        const float onemx2c = fmaxf(onemx2, EPSF);
        const float dot = acc[a][h2];
        const float c1 = fmaf(-2.f, dot, 1.f);
        const float A = c1 + y2c;
        const float den = fmaxf(fmaf(x2a, y2c, c1), EPSF);
        const float rd = rcp_fast(den);
        const float av = -A * rd;
        const float bv = onemx2 * rd;
        float un2 = av * av * x2a;
        un2 = fmaf(bv * bv, y2c, un2);
        un2 = fmaf(2.f * av * bv, dot, un2);
        un2 = fmaxf(un2, 0.f);
        float un = sqrtf(un2);
        un = fminf(fmaxf(un, EPSF), 1.0f - 1e-5f);
        const float ratio = (1.f + un) * rcp_fast(1.f - un);
        const float at = 0.34657359027997264f * __log2f(ratio);  // atanh(un)
        const float g = onemx2c * at * rcp_fast(un);
        const float sv = m ? g * av : 0.f;
        const float tv = m ? g * bv : 0.f;
        T[(size_t)(ib + a) * N + jcol] = tv;
        svsum[a] = sv;
    }

    // each wave owns one 4-row group x all 64 j: full-wave butterfly
#pragma unroll
    for (int off = 1; off < 64; off <<= 1) {
#pragma unroll
        for (int a = 0; a < 4; ++a) svsum[a] += __shfl_xor(svsum[a], off, 64);
    }
    if ((t & 63) == 0) {
#pragma unroll
        for (int a = 0; a < 4; ++a)
            alphaPart[(size_t)blockIdx.x * N + ib + a] = svsum[a];
    }
}

// K2: block = 4 rows, 256 blocks x 1024 thr (16 waves = 4 waves/SIMD).
// Wave w owns j-chunk [w*64, w*64+64); T row bases scalar (readfirstlane);
// each x load feeds 4 rows. Unroll 8: more independent L2 loads in flight.
__global__ __launch_bounds__(1024, 4) void out_kernel(
    const float* __restrict__ x, const float* __restrict__ T,
    const float* __restrict__ alphaPart, float* __restrict__ out) {
    const int N = 1024, D = 64;
    const int i0 = blockIdx.x * 4;
    const int w = threadIdx.x >> 6;     // 0..15
    const int d = threadIdx.x & 63;
    const int jw = __builtin_amdgcn_readfirstlane(w * 64);

    const float4* T0 = reinterpret_cast<const float4*>(T + (size_t)(i0 + 0) * N + jw);
    const float4* T1 = reinterpret_cast<const float4*>(T + (size_t)(i0 + 1) * N + jw);
    const float4* T2 = reinterpret_cast<const float4*>(T + (size_t)(i0 + 2) * N + jw);
    const float4* T3 = reinterpret_cast<const float4*>(T + (size_t)(i0 + 3) * N + jw);
    const float* xbase = x + (size_t)jw * D + d;

    float acc[4][4];
#pragma unroll
    for (int r = 0; r < 4; ++r)
#pragma unroll
        for (int c = 0; c < 4; ++c) acc[r][c] = 0.f;

#pragma unroll 8
    for (int q = 0; q < 16; ++q) {  // 64 j per wave, 4 per iter
        const float4 tq[4] = {T0[q], T1[q], T2[q], T3[q]};
        const float* xp = xbase + (size_t)q * 4 * D;
        const float x0 = xp[0 * D], x1 = xp[1 * D], x2v = xp[2 * D], x3 = xp[3 * D];
#pragma unroll
        for (int r = 0; r < 4; ++r) {
            acc[r][0] = fmaf(tq[r].x, x0, acc[r][0]);
            acc[r][1] = fmaf(tq[r].y, x1, acc[r][1]);
            acc[r][2] = fmaf(tq[r].z, x2v, acc[r][2]);
            acc[r][3] = fmaf(tq[r].w, x3, acc[r][3]);
        }
    }

    __shared__ float part[4][16][64];  // 16 KB
#pragma unroll
    for (int r = 0; r < 4; ++r)
        part[r][w][d] = (acc[r][0] + acc[r][1]) + (acc[r][2] + acc[r][3]);
    __syncthreads();

    if (threadIdx.x < 256) {
        const int r = threadIdx.x >> 6;  // wave r handles row i0+r
        const int i = i0 + r;
        float v = 0.f;
#pragma unroll
        for (int ww = 0; ww < 16; ++ww) v += part[r][ww][d];

        // alpha = sum of 16 j-tile partials
        float ap = (d < 16) ? alphaPart[(size_t)d * N + i] : 0.f;
#pragma unroll
        for (int off = 1; off < 64; off <<= 1) ap += __shfl_xor(ap, off, 64);

        const float xid = x[(size_t)i * D + d];
        float x2i = xid * xid;
#pragma unroll
        for (int off = 1; off < 64; off <<= 1) x2i += __shfl_xor(x2i, off, 64);
        const float onemx2 = 1.f - x2i;
        const float onemx2c = fmaxf(onemx2, EPSF);
        v = fmaf(ap, xid, v);

        // expmap(v, x_i)
        float vn2 = v * v;
#pragma unroll
        for (int off = 1; off < 64; off <<= 1) vn2 += __shfl_xor(vn2, off, 64);
        const float vn = fmaxf(sqrtf(vn2), EPSF);
        const float arg = vn * rcp_fast(onemx2c);
        const float th = tanhf(arg);
        const float sec = th * rcp_fast(vn) * v;

        // mobius_add(x_i, sec)
        float xy = xid * sec;
        float y2p = sec * sec;
#pragma unroll
        for (int off = 1; off < 64; off <<= 1) {
            xy += __shfl_xor(xy, off, 64);
            y2p += __shfl_xor(y2p, off, 64);
        }
        const float numd = (1.f + 2.f * xy + y2p) * xid + onemx2 * sec;
        const float den2 = fmaxf(fmaf(x2i, y2p, 1.f + 2.f * xy), EPSF);
        out[(size_t)i * D + d] = numd * rcp_fast(den2);
    }
}

extern "C" void kernel_launch(void* const* d_in, const int* in_sizes, int n_in,
                              void* d_out, int out_size, void* d_ws, size_t ws_size,
                              hipStream_t stream) {
    const float* x = (const float*)d_in[0];
    const int* adj = (const int*)d_in[1];
    float* out = (float*)d_out;
    const int N = 1024;

    float* T = (float*)d_ws;                                       // 4 MB
    float* alphaPart = (float*)((char*)d_ws + (size_t)N * N * 4);  // 64 KB

    hipLaunchKernelGGL(pair_kernel, dim3(16, 32), dim3(512), 0, stream, x, adj, T, alphaPart);
    hipLaunchKernelGGL(out_kernel, dim3(N / 4), dim3(1024), 0, stream, x, T, alphaPart, out);
}

// Round 12
// 19.551 us; speedup vs baseline: 1.0926x; 1.0926x over previous
//
#include <hip/hip_runtime.h>

#define EPSF 1e-7f

__device__ __forceinline__ float rcp_fast(float x) { return __builtin_amdgcn_rcpf(x); }

// LDS float4-chunk swizzle: spreads strided row reads across bank groups.
__device__ __forceinline__ int swz(int r, int c) { return r * 16 + (c ^ ((r >> 2) & 7)); }

__device__ __forceinline__ float dot4(float4 v) {
    return v.x * v.x + v.y * v.y + v.z * v.z + v.w * v.w;
}

// K1: 32(i) x 64(j) tile, 512 blocks x 512 threads = 4 waves/SIMD.
// Lane-quad micro-tile: thread (q, h2) computes 4x4 quarter-dots over dims
// [h2*16, h2*16+16); shfl_xor(1),(2) combine; lane h2 evaluates col jb+h2 for
// its 4 rows. (Round-10 configuration — best measured: 19.5 us.)
__global__ __launch_bounds__(512, 4) void pair_kernel(
    const float* __restrict__ x, const int* __restrict__ adj,
    float* __restrict__ T, float* __restrict__ alphaPart) {
    const int N = 1024;
    const int j0 = blockIdx.x * 64;
    const int i0 = blockIdx.y * 32;
    const int t = threadIdx.x;       // 0..511
    const int h2 = t & 3;            // dim quarter / col select
    const int q = t >> 2;            // 0..127
    const int qx = q & 15;           // j quad
    const int qy = q >> 4;           // 0..7, 4-row group

    __shared__ float4 ti4[32 * 16];  // 8 KB
    __shared__ float4 tj4[64 * 16];  // 16 KB
    __shared__ float x2i_l[32];
    __shared__ float y2_l[64];

    const float4* x4 = reinterpret_cast<const float4*>(x);
    {   // ti: 512 float4, one pass
        const int r = t >> 4, c = t & 15;
        float4 v = x4[(size_t)i0 * 16 + t];
        ti4[swz(r, c)] = v;
        float s = dot4(v);
#pragma unroll
        for (int off = 1; off <= 8; off <<= 1) s += __shfl_xor(s, off, 64);
        if ((t & 15) == 0) x2i_l[r] = s;
    }
#pragma unroll
    for (int k = 0; k < 2; ++k) {  // tj: 1024 float4, two passes
        const int f = k * 512 + t;
        const int r = f >> 4, c = f & 15;
        float4 v = x4[(size_t)j0 * 16 + f];
        tj4[swz(r, c)] = v;
        float s = dot4(v);
#pragma unroll
        for (int off = 1; off <= 8; off <<= 1) s += __shfl_xor(s, off, 64);
        if ((t & 15) == 0) y2_l[r] = s;
    }
    __syncthreads();

    float acc[4][4];
#pragma unroll
    for (int a = 0; a < 4; ++a)
#pragma unroll
        for (int b = 0; b < 4; ++b) acc[a][b] = 0.f;

#pragma unroll
    for (int cc = 0; cc < 4; ++cc) {
        const int c = h2 * 4 + cc;
        float4 xiv[4], xjv[4];
#pragma unroll
        for (int a = 0; a < 4; ++a) xiv[a] = ti4[swz(qy * 4 + a, c)];
#pragma unroll
        for (int b = 0; b < 4; ++b) xjv[b] = tj4[swz(qx * 4 + b, c)];
#pragma unroll
        for (int a = 0; a < 4; ++a)
#pragma unroll
            for (int b = 0; b < 4; ++b) {
                acc[a][b] = fmaf(xiv[a].x, xjv[b].x, acc[a][b]);
                acc[a][b] = fmaf(xiv[a].y, xjv[b].y, acc[a][b]);
                acc[a][b] = fmaf(xiv[a].z, xjv[b].z, acc[a][b]);
                acc[a][b] = fmaf(xiv[a].w, xjv[b].w, acc[a][b]);
            }
    }
    // combine dim-quarters (lane bits 0,1): all quad lanes end with full dots
#pragma unroll
    for (int a = 0; a < 4; ++a)
#pragma unroll
        for (int b = 0; b < 4; ++b) {
            acc[a][b] += __shfl_xor(acc[a][b], 1, 64);
            acc[a][b] += __shfl_xor(acc[a][b], 2, 64);
        }

    const int ib = i0 + qy * 4;
    const int jb = j0 + qx * 4;
    const int jcol = jb + h2;        // this lane's column
    const float y2c = y2_l[qx * 4 + h2];

    float svsum[4];
#pragma unroll
    for (int a = 0; a < 4; ++a) {
        const int m = adj[(size_t)(ib + a) * N + jcol];
        const float x2a = x2i_l[qy * 4 + a];
        const float onemx2 = 1.f - x2a;
        const float onemx2c = fmaxf(onemx2, EPSF);
        const float dot = acc[a][h2];
        const float c1 = fmaf(-2.f, dot, 1.f);
        const float A = c1 + y2c;
        const float den = fmaxf(fmaf(x2a, y2c, c1), EPSF);
        const float rd = rcp_fast(den);
        const float av = -A * rd;
        const float bv = onemx2 * rd;
        float un2 = av * av * x2a;
        un2 = fmaf(bv * bv, y2c, un2);
        un2 = fmaf(2.f * av * bv, dot, un2);
        un2 = fmaxf(un2, 0.f);
        float un = sqrtf(un2);
        un = fminf(fmaxf(un, EPSF), 1.0f - 1e-5f);
        const float ratio = (1.f + un) * rcp_fast(1.f - un);
        const float at = 0.34657359027997264f * __log2f(ratio);  // atanh(un)
        const float g = onemx2c * at * rcp_fast(un);
        const float sv = m ? g * av : 0.f;
        const float tv = m ? g * bv : 0.f;
        T[(size_t)(ib + a) * N + jcol] = tv;
        svsum[a] = sv;
    }

    // each wave owns one 4-row group x all 64 j: full-wave butterfly
#pragma unroll
    for (int off = 1; off < 64; off <<= 1) {
#pragma unroll
        for (int a = 0; a < 4; ++a) svsum[a] += __shfl_xor(svsum[a], off, 64);
    }
    if ((t & 63) == 0) {
#pragma unroll
        for (int a = 0; a < 4; ++a)
            alphaPart[(size_t)blockIdx.x * N + ib + a] = svsum[a];
    }
}

// K2: block = 4 rows, 256 blocks x 1024 thr (16 waves, 1 block/CU = 4 waves/SIMD).
// Wave w owns j-chunk [w*64, w*64+64); T row bases scalar (readfirstlane);
// each x load feeds 4 rows. x traffic 64 MB via L2.
__global__ __launch_bounds__(1024, 4) void out_kernel(
    const float* __restrict__ x, const float* __restrict__ T,
    const float* __restrict__ alphaPart, float* __restrict__ out) {
    const int N = 1024, D = 64;
    const int i0 = blockIdx.x * 4;
    const int w = threadIdx.x >> 6;     // 0..15
    const int d = threadIdx.x & 63;
    const int jw = __builtin_amdgcn_readfirstlane(w * 64);

    const float4* T0 = reinterpret_cast<const float4*>(T + (size_t)(i0 + 0) * N + jw);
    const float4* T1 = reinterpret_cast<const float4*>(T + (size_t)(i0 + 1) * N + jw);
    const float4* T2 = reinterpret_cast<const float4*>(T + (size_t)(i0 + 2) * N + jw);
    const float4* T3 = reinterpret_cast<const float4*>(T + (size_t)(i0 + 3) * N + jw);
    const float* xbase = x + (size_t)jw * D + d;

    float acc[4][4];
#pragma unroll
    for (int r = 0; r < 4; ++r)
#pragma unroll
        for (int c = 0; c < 4; ++c) acc[r][c] = 0.f;

#pragma unroll 4
    for (int q = 0; q < 16; ++q) {  // 64 j per wave, 4 per iter
        const float4 tq[4] = {T0[q], T1[q], T2[q], T3[q]};
        const float* xp = xbase + (size_t)q * 4 * D;
        const float x0 = xp[0 * D], x1 = xp[1 * D], x2v = xp[2 * D], x3 = xp[3 * D];
#pragma unroll
        for (int r = 0; r < 4; ++r) {
            acc[r][0] = fmaf(tq[r].x, x0, acc[r][0]);
            acc[r][1] = fmaf(tq[r].y, x1, acc[r][1]);
            acc[r][2] = fmaf(tq[r].z, x2v, acc[r][2]);
            acc[r][3] = fmaf(tq[r].w, x3, acc[r][3]);
        }
    }

    __shared__ float part[4][16][64];  // 16 KB
#pragma unroll
    for (int r = 0; r < 4; ++r)
        part[r][w][d] = (acc[r][0] + acc[r][1]) + (acc[r][2] + acc[r][3]);
    __syncthreads();

    if (threadIdx.x < 256) {
        const int r = threadIdx.x >> 6;  // wave r handles row i0+r
        const int i = i0 + r;
        float v = 0.f;
#pragma unroll
        for (int ww = 0; ww < 16; ++ww) v += part[r][ww][d];

        // alpha = sum of 16 j-tile partials
        float ap = (d < 16) ? alphaPart[(size_t)d * N + i] : 0.f;
#pragma unroll
        for (int off = 1; off < 64; off <<= 1) ap += __shfl_xor(ap, off, 64);

        const float xid = x[(size_t)i * D + d];
        float x2i = xid * xid;
#pragma unroll
        for (int off = 1; off < 64; off <<= 1) x2i += __shfl_xor(x2i, off, 64);
        const float onemx2 = 1.f - x2i;
        const float onemx2c = fmaxf(onemx2, EPSF);
        v = fmaf(ap, xid, v);

        // expmap(v, x_i)
        float vn2 = v * v;
#pragma unroll
        for (int off = 1; off < 64; off <<= 1) vn2 += __shfl_xor(vn2, off, 64);
        const float vn = fmaxf(sqrtf(vn2), EPSF);
        const float arg = vn * rcp_fast(onemx2c);
        const float th = tanhf(arg);
        const float sec = th * rcp_fast(vn) * v;

        // mobius_add(x_i, sec)
        float xy = xid * sec;
        float y2p = sec * sec;
#pragma unroll
        for (int off = 1; off < 64; off <<= 1) {
            xy += __shfl_xor(xy, off, 64);
            y2p += __shfl_xor(y2p, off, 64);
        }
        const float numd = (1.f + 2.f * xy + y2p) * xid + onemx2 * sec;
        const float den2 = fmaxf(fmaf(x2i, y2p, 1.f + 2.f * xy), EPSF);
        out[(size_t)i * D + d] = numd * rcp_fast(den2);
    }
}

extern "C" void kernel_launch(void* const* d_in, const int* in_sizes, int n_in,
                              void* d_out, int out_size, void* d_ws, size_t ws_size,
                              hipStream_t stream) {
    const float* x = (const float*)d_in[0];
    const int* adj = (const int*)d_in[1];
    float* out = (float*)d_out;
    const int N = 1024;

    float* T = (float*)d_ws;                                       // 4 MB
    float* alphaPart = (float*)((char*)d_ws + (size_t)N * N * 4);  // 64 KB

    hipLaunchKernelGGL(pair_kernel, dim3(16, 32), dim3(512), 0, stream, x, adj, T, alphaPart);
    hipLaunchKernelGGL(out_kernel, dim3(N / 4), dim3(1024), 0, stream, x, T, alphaPart, out);
}